// Round 4
// baseline (238.241 us; speedup 1.0000x reference)
//
#include <hip/hip_runtime.h>

#define N_SEQ 1024
#define B_SZ 8
#define C_DIM 256
#define K_HEADS 4
#define FF_DIM 2048

typedef short s16x8 __attribute__((ext_vector_type(8)));
typedef float f32x4v __attribute__((ext_vector_type(4)));

#define GLOAD_LDS16(src, dst)                                                              \
    __builtin_amdgcn_global_load_lds((const __attribute__((address_space(1))) void*)(src), \
                                     (__attribute__((address_space(3))) void*)(dst), 16, 0, 0)

__device__ __forceinline__ unsigned short f2bf(float f) {
    unsigned u = __builtin_bit_cast(unsigned, f);
    u += 0x7FFFu + ((u >> 16) & 1u);
    return (unsigned short)(u >> 16);
}
__device__ __forceinline__ float bf2f(unsigned short h) {
    unsigned u = ((unsigned)h) << 16;
    return __builtin_bit_cast(float, u);
}

// ---------------- prep kernels ----------------

__global__ __launch_bounds__(256) void prep_q_kernel(const float* __restrict__ src,
                                                     const float* __restrict__ pos,
                                                     unsigned short* __restrict__ qb) {
    int t = blockIdx.x * 256 + threadIdx.x;
    int i4 = t * 4;
    int n = i4 >> 11;
    int rem = i4 & 2047;
    int b = rem >> 8;
    int c = rem & 255;
    float4 s = *reinterpret_cast<const float4*>(src + i4);
    float4 p = *reinterpret_cast<const float4*>(pos + i4);
    int out = (b * N_SEQ + n) * C_DIM + c;
    *reinterpret_cast<ushort4*>(qb + out) = make_ushort4(
        f2bf((s.x + p.x) * 0.0625f), f2bf((s.y + p.y) * 0.0625f),
        f2bf((s.z + p.z) * 0.0625f), f2bf((s.w + p.w) * 0.0625f));
}

// One block per (k,b,ntile of 64): writes kb row-major (+pos) and vbT transposed [pair][c][n].
__global__ __launch_bounds__(256) void prep_kv_kernel(const float* __restrict__ matched,
                                                      const float* __restrict__ pos,
                                                      unsigned short* __restrict__ kb,
                                                      unsigned short* __restrict__ vbT) {
    __shared__ unsigned short Vl[64][256];
    int blk = blockIdx.x;
    int nt = blk & 15, pr = blk >> 4;          // pr = k*8+b
    int k = pr >> 3, b = pr & 7;
    int n0 = nt * 64;
    int t = threadIdx.x;
    int c4 = (t & 63) * 4;
#pragma unroll
    for (int r = 0; r < 16; r++) {
        int nl = (t >> 6) * 16 + r;
        int n = n0 + nl;
        size_t mi = ((size_t)(k * N_SEQ + n) * B_SZ + b) * C_DIM + c4;
        float4 m = *reinterpret_cast<const float4*>(matched + mi);
        float4 p = *reinterpret_cast<const float4*>(pos + ((size_t)n * B_SZ + b) * C_DIM + c4);
        *reinterpret_cast<ushort4*>(kb + ((size_t)pr * N_SEQ + n) * C_DIM + c4) =
            make_ushort4(f2bf(m.x + p.x), f2bf(m.y + p.y), f2bf(m.z + p.z), f2bf(m.w + p.w));
        *reinterpret_cast<ushort4*>(&Vl[nl][c4]) =
            make_ushort4(f2bf(m.x), f2bf(m.y), f2bf(m.z), f2bf(m.w));
    }
    __syncthreads();
    unsigned short* vrow = vbT + ((size_t)pr * C_DIM + t) * N_SEQ + n0;
#pragma unroll
    for (int g = 0; g < 8; g++) {
        s16x8 v;
#pragma unroll
        for (int j = 0; j < 8; j++) v[j] = (short)Vl[g * 8 + j][t];
        *reinterpret_cast<s16x8*>(vrow + g * 8) = v;
    }
}

__global__ __launch_bounds__(256) void transpose_w_kernel(const float* __restrict__ W,
                                                          unsigned short* __restrict__ Wt,
                                                          int R, int Cn) {
    int idx = blockIdx.x * 256 + threadIdx.x;
    int c = idx / R;
    int r = idx - c * R;
    Wt[idx] = f2bf(W[(size_t)r * Cn + c]);
}

// ---------------- flash attention (KV-split x2) ----------------
// grid = 1024 blocks (XCD-aware mapping, kidx minor), 256 threads.
// Each block: one (b, qt, half, kidx); 16 KV tiles of 32; writes l-normalized
// partial O (bf16) + (m,l) f32.
__global__ __launch_bounds__(256) void attn_kernel(const unsigned short* __restrict__ qb,
                                                   const unsigned short* __restrict__ kb,
                                                   const unsigned short* __restrict__ vbT,
                                                   const float* __restrict__ mask,
                                                   unsigned short* __restrict__ op0,
                                                   unsigned short* __restrict__ op1,
                                                   float2* __restrict__ mlb) {
    __shared__ unsigned short Kl[2][32 * 256];   // 32 KB: linear, XOR-swizzled (gload_lds)
    __shared__ unsigned short VlF[8192];         // 16 KB: [ct=16][ks=4][l15=16] x 16B fragments
    __shared__ unsigned short Pl[4][16][36];     // 4.6 KB: wave-private P

    // XCD-aware decode: 4 kidx-sharers of one (b,qt,half) land on the same XCD (%8)
    int bx = blockIdx.x;
    int x = bx & 7;
    int j = bx >> 3;
    int kidx = j & 3;
    int g = (j >> 2) * 8 + x;        // 0..255
    int qt = g & 15;
    int b = (g >> 4) & 7;
    int half = g >> 7;
    int pr = kidx * 8 + b;

    int tid = threadIdx.x, wid = tid >> 6, lane = tid & 63;
    int l15 = lane & 15, lg = lane >> 4;
    int q0 = qt * 64 + wid * 16;
    int kvh = half * 512;

    // Q fragments
    s16x8 qf[8];
    const unsigned short* qrow = qb + ((size_t)(b * N_SEQ + q0 + l15)) * C_DIM + lg * 8;
#pragma unroll
    for (int cc = 0; cc < 8; cc++) qf[cc] = *reinterpret_cast<const s16x8*>(qrow + cc * 32);

    f32x4v oacc[16];
#pragma unroll
    for (int i = 0; i < 16; i++) oacc[i] = (f32x4v){0.f, 0.f, 0.f, 0.f};
    float mrun = -3e38f, lrun = 0.f;

    size_t kvbase = (size_t)pr * N_SEQ * C_DIM;
    const unsigned short* kbp = kb + kvbase;
    const unsigned short* vtp = vbT + ((size_t)pr * C_DIM + tid) * N_SEQ + kvh;
    const float* mrow = mask + ((size_t)b * N_SEQ + q0 + l15) * N_SEQ + kvh;

    auto stage_k = [&](int kv0, unsigned short* buf) {
#pragma unroll
        for (int i = 0; i < 4; i++) {
            int ch = (wid * 4 + i) * 64 + lane;
            int r = ch >> 5;
            int ce = ((ch & 31) * 8) ^ ((r & 7) << 3);
            GLOAD_LDS16(kbp + (size_t)(kvh + kv0 + r) * C_DIM + ce, &buf[(wid * 4 + i) * 512]);
        }
    };

    // prologue: K tile 0 via gload_lds; V tile 0 + mask tile 0 into regs
    s16x8 vr[4];
    stage_k(0, &Kl[0][0]);
#pragma unroll
    for (int c = 0; c < 4; c++) vr[c] = *reinterpret_cast<const s16x8*>(vtp + c * 8);
    f32x4v mc0 = *reinterpret_cast<const f32x4v*>(mrow + lg * 4);
    f32x4v mc1 = *reinterpret_cast<const f32x4v*>(mrow + 16 + lg * 4);

    int swz = (l15 & 7) << 3;
    unsigned short* vdst = VlF + ((tid >> 4) * 512 + (tid & 15) * 8);
    for (int t = 0; t < 16; t++) {
        int cur = t & 1;
        int kv0 = t * 32;
        __syncthreads();                         // (A) K[t] staged; prefetches drained; VlF free
        // write V fragment tile (lane-consecutive 16B -> conflict-free)
#pragma unroll
        for (int ks = 0; ks < 4; ks++)
            *reinterpret_cast<s16x8*>(vdst + ks * 128) = vr[ks];

        // S^T = K Q^T
        f32x4v s0 = {0.f, 0.f, 0.f, 0.f}, s1 = {0.f, 0.f, 0.f, 0.f};
        const unsigned short* KlB = &Kl[cur][0];
#pragma unroll
        for (int cc = 0; cc < 8; cc++) {
            s16x8 k0 = *reinterpret_cast<const s16x8*>(KlB + l15 * 256 + ((cc * 32 + lg * 8) ^ swz));
            s16x8 k1 = *reinterpret_cast<const s16x8*>(KlB + (16 + l15) * 256 + ((cc * 32 + lg * 8) ^ swz));
            s0 = __builtin_amdgcn_mfma_f32_16x16x32_bf16(k0, qf[cc], s0, 0, 0, 0);
            s1 = __builtin_amdgcn_mfma_f32_16x16x32_bf16(k1, qf[cc], s1, 0, 0, 0);
        }
#pragma unroll
        for (int jj = 0; jj < 4; jj++) { s0[jj] += mc0[jj]; s1[jj] += mc1[jj]; }

        // online softmax over kv (in-lane 8 + xor 16/32)
        float pm = fmaxf(fmaxf(fmaxf(s0[0], s0[1]), fmaxf(s0[2], s0[3])),
                         fmaxf(fmaxf(s1[0], s1[1]), fmaxf(s1[2], s1[3])));
        pm = fmaxf(pm, __shfl_xor(pm, 16));
        pm = fmaxf(pm, __shfl_xor(pm, 32));
        if (__any(pm > mrun + 8.f)) {            // defer-max
            float mn = fmaxf(mrun, pm);
            float sc = __expf(mrun - mn);
            mrun = mn;
            lrun *= sc;
#pragma unroll
            for (int ct = 0; ct < 16; ct++)
#pragma unroll
                for (int jj = 0; jj < 4; jj++) oacc[ct][jj] *= sc;
        }
        float p0[4], p1[4];
#pragma unroll
        for (int jj = 0; jj < 4; jj++) {
            p0[jj] = __expf(s0[jj] - mrun);
            p1[jj] = __expf(s1[jj] - mrun);
        }
        float ps = (p0[0] + p0[1]) + (p0[2] + p0[3]) + (p1[0] + p1[1]) + (p1[2] + p1[3]);
        ps += __shfl_xor(ps, 16);
        ps += __shfl_xor(ps, 32);
        lrun += ps;

        __syncthreads();                         // (B) VlF visible; QK reads of Kl[cur] done

        // prefetch t+1 (issued after B; drained at next A; covered by P+PV)
        if (t + 1 < 16) {
            stage_k(kv0 + 32, &Kl[cur ^ 1][0]);
#pragma unroll
            for (int c = 0; c < 4; c++)
                vr[c] = *reinterpret_cast<const s16x8*>(vtp + kv0 + 32 + c * 8);
            mc0 = *reinterpret_cast<const f32x4v*>(mrow + kv0 + 32 + lg * 4);
            mc1 = *reinterpret_cast<const f32x4v*>(mrow + kv0 + 48 + lg * 4);
        }

        // P^T -> Pl (wave-private) -> A-fragment for PV
        *reinterpret_cast<ushort4*>(&Pl[wid][l15][lg * 4]) =
            make_ushort4(f2bf(p0[0]), f2bf(p0[1]), f2bf(p0[2]), f2bf(p0[3]));
        *reinterpret_cast<ushort4*>(&Pl[wid][l15][16 + lg * 4]) =
            make_ushort4(f2bf(p1[0]), f2bf(p1[1]), f2bf(p1[2]), f2bf(p1[3]));
        s16x8 pf = *reinterpret_cast<const s16x8*>(&Pl[wid][l15][lg * 8]);

        // O^T += V^T P^T (A-fragments lane-consecutive -> conflict-free)
#pragma unroll
        for (int ct = 0; ct < 16; ct++) {
            s16x8 af = *reinterpret_cast<const s16x8*>(VlF + ct * 512 + lg * 128 + l15 * 8);
            oacc[ct] = __builtin_amdgcn_mfma_f32_16x16x32_bf16(af, pf, oacc[ct], 0, 0, 0);
        }
    }

    float inv = 1.0f / lrun;
    unsigned short* Op = half ? op1 : op0;
    size_t orow = ((size_t)(b * N_SEQ + q0 + l15)) * (K_HEADS * C_DIM) + kidx * C_DIM + lg * 4;
#pragma unroll
    for (int ct = 0; ct < 16; ct++) {
        *reinterpret_cast<ushort4*>(Op + orow + ct * 16) =
            make_ushort4(f2bf(oacc[ct][0] * inv), f2bf(oacc[ct][1] * inv),
                         f2bf(oacc[ct][2] * inv), f2bf(oacc[ct][3] * inv));
    }
    if (lg == 0)
        mlb[((size_t)(half * 4 + kidx) * 8 + b) * N_SEQ + q0 + l15] = make_float2(mrun, lrun);
}

// ---------------- combine two KV-half partials ----------------
__global__ __launch_bounds__(256) void combine_kernel(const unsigned short* __restrict__ op0,
                                                      const unsigned short* __restrict__ op1,
                                                      const float2* __restrict__ mlb,
                                                      unsigned short* __restrict__ att) {
    int t = blockIdx.x * 256 + threadIdx.x;      // 1,048,576 threads, 8 elems each
    int kidx = (t >> 5) & 3;
    int bn = t >> 7;                             // b*N + n
    int n = bn & 1023, b = bn >> 10;
    float2 e0 = mlb[((size_t)kidx * 8 + b) * N_SEQ + n];
    float2 e1 = mlb[((size_t)(4 + kidx) * 8 + b) * N_SEQ + n];
    float M = fmaxf(e0.x, e1.x);
    float w0 = e0.y * __expf(e0.x - M);
    float w1 = e1.y * __expf(e1.x - M);
    float r = 1.0f / (w0 + w1);
    w0 *= r;
    w1 *= r;
    s16x8 a = *reinterpret_cast<const s16x8*>(op0 + (size_t)t * 8);
    s16x8 c = *reinterpret_cast<const s16x8*>(op1 + (size_t)t * 8);
    s16x8 o;
#pragma unroll
    for (int i = 0; i < 8; i++)
        o[i] = (short)f2bf(w0 * bf2f((unsigned short)a[i]) + w1 * bf2f((unsigned short)c[i]));
    *reinterpret_cast<s16x8*>(att + (size_t)t * 8) = o;
}

// ---------------- GEMM: C = A(MxK) * Bt(NxK)^T + bias ----------------
template <int BM, int BN, int RELU, int OUTBF>
__global__ __launch_bounds__(256) void gemm_bt_kernel(const unsigned short* __restrict__ A,
                                                      const unsigned short* __restrict__ Bt,
                                                      const float* __restrict__ bias,
                                                      float* __restrict__ Cf,
                                                      unsigned short* __restrict__ Cb,
                                                      int M, int Nn, int Kd) {
    constexpr int WAVES_N = (BM == 128) ? 2 : 4;
    constexpr int WN = BN / WAVES_N;
    constexpr int NT = WN / 16;
    constexpr int TILE = (BM + BN) * 64;
    constexpr int CALLS = (BM + BN) / 32;
    __shared__ unsigned short Sl[2][TILE];
    int tm0 = blockIdx.y * BM, tn0 = blockIdx.x * BN;
    int tid = threadIdx.x, wid = tid >> 6, lane = tid & 63;
    int l15 = lane & 15, lg = lane >> 4;
    int wm = (wid / WAVES_N) * 64, wn = (wid % WAVES_N) * WN;

    f32x4v acc[4][NT];
#pragma unroll
    for (int i = 0; i < 4; i++)
#pragma unroll
        for (int j = 0; j < NT; j++) acc[i][j] = (f32x4v){0.f, 0.f, 0.f, 0.f};

    auto stage = [&](int k0, unsigned short* buf) {
#pragma unroll
        for (int i = 0; i < CALLS; i++) {
            int chb = (i * 4 + wid) * 64;
            int ch = chb + lane;
            const unsigned short* src;
            if (chb < BM * 8) {
                int r = ch >> 3;
                int c8 = ((ch & 7) * 8) ^ ((r & 7) << 3);
                src = A + (size_t)(tm0 + r) * Kd + k0 + c8;
            } else {
                int ch2 = ch - BM * 8;
                int r = ch2 >> 3;
                int c8 = ((ch2 & 7) * 8) ^ ((r & 7) << 3);
                src = Bt + (size_t)(tn0 + r) * Kd + k0 + c8;
            }
            GLOAD_LDS16(src, buf + chb * 8);
        }
    };

    stage(0, &Sl[0][0]);
    int nk = Kd >> 6;
    int swz = (l15 & 7) << 3;
    for (int kt = 0; kt < nk; kt++) {
        int cur = kt & 1;
        __syncthreads();
        if (kt + 1 < nk) stage((kt + 1) * 64, &Sl[cur ^ 1][0]);
        const unsigned short* SA = &Sl[cur][0];
        const unsigned short* SB = SA + BM * 64;
        s16x8 af[4][2], bf[NT][2];
#pragma unroll
        for (int mt = 0; mt < 4; mt++)
#pragma unroll
            for (int h = 0; h < 2; h++)
                af[mt][h] = *reinterpret_cast<const s16x8*>(
                    SA + (wm + mt * 16 + l15) * 64 + ((h * 32 + lg * 8) ^ swz));
#pragma unroll
        for (int nt = 0; nt < NT; nt++)
#pragma unroll
            for (int h = 0; h < 2; h++)
                bf[nt][h] = *reinterpret_cast<const s16x8*>(
                    SB + (wn + nt * 16 + l15) * 64 + ((h * 32 + lg * 8) ^ swz));
#pragma unroll
        for (int mt = 0; mt < 4; mt++)
#pragma unroll
            for (int nt = 0; nt < NT; nt++) {
                acc[mt][nt] = __builtin_amdgcn_mfma_f32_16x16x32_bf16(af[mt][0], bf[nt][0], acc[mt][nt], 0, 0, 0);
                acc[mt][nt] = __builtin_amdgcn_mfma_f32_16x16x32_bf16(af[mt][1], bf[nt][1], acc[mt][nt], 0, 0, 0);
            }
    }

#pragma unroll
    for (int mt = 0; mt < 4; mt++) {
#pragma unroll
        for (int nt = 0; nt < NT; nt++) {
#pragma unroll
            for (int j = 0; j < 4; j++) {
                int row = tm0 + wm + mt * 16 + lg * 4 + j;
                int col = tn0 + wn + nt * 16 + l15;
                float v = acc[mt][nt][j] + bias[col];
                if (RELU) v = fmaxf(v, 0.f);
                if (OUTBF) Cb[(size_t)row * Nn + col] = f2bf(v);
                else       Cf[(size_t)row * Nn + col] = v;
            }
        }
    }
}

// ---------------- fused residual + LayerNorm ----------------
__global__ __launch_bounds__(256) void ln1_kernel(const float* __restrict__ src,
                                                  const float* __restrict__ recT,
                                                  const float* __restrict__ g,
                                                  const float* __restrict__ be,
                                                  float* __restrict__ outf,
                                                  unsigned short* __restrict__ outb) {
    int r = blockIdx.x * 4 + (threadIdx.x >> 6);
    int lane = threadIdx.x & 63;
    int n = r >> 3, b = r & 7;
    int c = lane * 4;
    float4 xs = *reinterpret_cast<const float4*>(src + (size_t)r * C_DIM + c);
    float4 xr = *reinterpret_cast<const float4*>(recT + ((size_t)(b * N_SEQ + n)) * C_DIM + c);
    float x[4] = {xs.x + xr.x, xs.y + xr.y, xs.z + xr.z, xs.w + xr.w};
    float s = x[0] + x[1] + x[2] + x[3];
    float q = x[0] * x[0] + x[1] * x[1] + x[2] * x[2] + x[3] * x[3];
#pragma unroll
    for (int d = 1; d < 64; d <<= 1) {
        s += __shfl_xor(s, d);
        q += __shfl_xor(q, d);
    }
    float mean = s * (1.f / 256.f);
    float var = q * (1.f / 256.f) - mean * mean;
    float rstd = rsqrtf(var + 1e-5f);
    float4 gv = *reinterpret_cast<const float4*>(g + c);
    float4 bv = *reinterpret_cast<const float4*>(be + c);
    float y0 = (x[0] - mean) * rstd * gv.x + bv.x;
    float y1 = (x[1] - mean) * rstd * gv.y + bv.y;
    float y2 = (x[2] - mean) * rstd * gv.z + bv.z;
    float y3 = (x[3] - mean) * rstd * gv.w + bv.w;
    *reinterpret_cast<float4*>(outf + (size_t)r * C_DIM + c) = make_float4(y0, y1, y2, y3);
    *reinterpret_cast<ushort4*>(outb + (size_t)r * C_DIM + c) =
        make_ushort4(f2bf(y0), f2bf(y1), f2bf(y2), f2bf(y3));
}

__global__ __launch_bounds__(256) void ln2_kernel(const float* __restrict__ rec1f,
                                                  const float* __restrict__ ffn,
                                                  const float* __restrict__ g,
                                                  const float* __restrict__ be,
                                                  float* __restrict__ out) {
    int r = blockIdx.x * 4 + (threadIdx.x >> 6);
    int lane = threadIdx.x & 63;
    int c = lane * 4;
    size_t base = (size_t)r * C_DIM + c;
    float4 xa = *reinterpret_cast<const float4*>(rec1f + base);
    float4 xb = *reinterpret_cast<const float4*>(ffn + base);
    float x[4] = {xa.x + xb.x, xa.y + xb.y, xa.z + xb.z, xa.w + xb.w};
    float s = x[0] + x[1] + x[2] + x[3];
    float q = x[0] * x[0] + x[1] * x[1] + x[2] * x[2] + x[3] * x[3];
#pragma unroll
    for (int d = 1; d < 64; d <<= 1) {
        s += __shfl_xor(s, d);
        q += __shfl_xor(q, d);
    }
    float mean = s * (1.f / 256.f);
    float var = q * (1.f / 256.f) - mean * mean;
    float rstd = rsqrtf(var + 1e-5f);
    float4 gv = *reinterpret_cast<const float4*>(g + c);
    float4 bv = *reinterpret_cast<const float4*>(be + c);
    *reinterpret_cast<float4*>(out + base) = make_float4(
        (x[0] - mean) * rstd * gv.x + bv.x,
        (x[1] - mean) * rstd * gv.y + bv.y,
        (x[2] - mean) * rstd * gv.z + bv.z,
        (x[3] - mean) * rstd * gv.w + bv.w);
}

// ---------------- launch ----------------

extern "C" void kernel_launch(void* const* d_in, const int* in_sizes, int n_in,
                              void* d_out, int out_size, void* d_ws, size_t ws_size,
                              hipStream_t stream) {
    const float* src   = (const float*)d_in[0];
    const float* match = (const float*)d_in[1];
    const float* pos   = (const float*)d_in[2];
    const float* mask  = (const float*)d_in[3];
    const float* Wagg  = (const float*)d_in[4];
    const float* bagg  = (const float*)d_in[5];
    const float* W1    = (const float*)d_in[6];
    const float* b1    = (const float*)d_in[7];
    const float* W2    = (const float*)d_in[8];
    const float* b2    = (const float*)d_in[9];
    const float* g1    = (const float*)d_in[10];
    const float* be1   = (const float*)d_in[11];
    const float* g2    = (const float*)d_in[12];
    const float* be2   = (const float*)d_in[13];

    char* ws = (char*)d_ws;
    unsigned short* qb    = (unsigned short*)(ws + 0);          //  4 MB (B,N,C) bf16 pre-scaled
    unsigned short* kb    = (unsigned short*)(ws + 4194304);    // 16 MB (K*B,N,C) bf16
    unsigned short* vbT   = (unsigned short*)(ws + 20971520);   // 16 MB (K*B,C,N) bf16 transposed
    unsigned short* att   = (unsigned short*)(ws + 37748736);   // 16 MB (B,N,K*C) bf16; = op0
    float*          rec_t = (float*)(ws + 57147392);            // 8 MB (B*N,C) f32
    float*          rec1f = (float*)(ws + 65536000);            // 8 MB (N*B,C) f32
    unsigned short* rec1b = (unsigned short*)(ws + 73924608);   // 4 MB bf16
    unsigned short* WaggT = (unsigned short*)(ws + 54525952);   // 0.5 MB
    unsigned short* W1T   = (unsigned short*)(ws + 55050240);   // 1 MB
    unsigned short* W2T   = (unsigned short*)(ws + 56098816);   // 1 MB
    // attention-phase aliases (dead regions during attn):
    unsigned short* op0   = att;                                // 16 MB partial half0 (combined in-place)
    unsigned short* op1   = (unsigned short*)(ws + 57147392);   // 16 MB partial half1 (over rec_t+rec1f)
    float2*         mlb   = (float2*)(ws + 73924608);           // 512 KB (over rec1b)
    unsigned short* hid   = (unsigned short*)(ws + 4194304);    // 32 MB, aliases kb+vbT (dead post-attn)
    float*          ffn   = (float*)(ws + 57147392);            // 8 MB, aliases rec_t (dead)
    float* outp = (float*)d_out;

    prep_q_kernel<<<2048, 256, 0, stream>>>(src, pos, qb);
    prep_kv_kernel<<<512, 256, 0, stream>>>(match, pos, kb, vbT);
    transpose_w_kernel<<<1024, 256, 0, stream>>>(Wagg, WaggT, K_HEADS * C_DIM, C_DIM);
    transpose_w_kernel<<<2048, 256, 0, stream>>>(W1, W1T, C_DIM, FF_DIM);
    transpose_w_kernel<<<2048, 256, 0, stream>>>(W2, W2T, FF_DIM, C_DIM);

    attn_kernel<<<1024, 256, 0, stream>>>(qb, kb, vbT, mask, op0, op1, mlb);
    combine_kernel<<<4096, 256, 0, stream>>>(op0, op1, mlb, att);

    gemm_bt_kernel<64, 128, 0, 0><<<dim3(2, 128), 256, 0, stream>>>(
        att, WaggT, bagg, rec_t, nullptr, B_SZ * N_SEQ, C_DIM, K_HEADS * C_DIM);
    ln1_kernel<<<2048, 256, 0, stream>>>(src, rec_t, g1, be1, rec1f, rec1b);
    gemm_bt_kernel<128, 128, 1, 1><<<dim3(16, 64), 256, 0, stream>>>(
        rec1b, W1T, b1, nullptr, hid, N_SEQ * B_SZ, FF_DIM, C_DIM);
    gemm_bt_kernel<64, 128, 0, 0><<<dim3(2, 128), 256, 0, stream>>>(
        hid, W2T, b2, ffn, nullptr, N_SEQ * B_SZ, C_DIM, FF_DIM);
    ln2_kernel<<<2048, 256, 0, stream>>>(rec1f, ffn, g2, be2, outp);
}

// Round 5
// 220.120 us; speedup vs baseline: 1.0823x; 1.0823x over previous
//
#include <hip/hip_runtime.h>

#define N_SEQ 1024
#define B_SZ 8
#define C_DIM 256
#define K_HEADS 4
#define FF_DIM 2048

typedef short s16x8 __attribute__((ext_vector_type(8)));
typedef float f32x4v __attribute__((ext_vector_type(4)));

#define GLOAD_LDS16(src, dst)                                                              \
    __builtin_amdgcn_global_load_lds((const __attribute__((address_space(1))) void*)(src), \
                                     (__attribute__((address_space(3))) void*)(dst), 16, 0, 0)

__device__ __forceinline__ unsigned short f2bf(float f) {
    unsigned u = __builtin_bit_cast(unsigned, f);
    u += 0x7FFFu + ((u >> 16) & 1u);
    return (unsigned short)(u >> 16);
}
__device__ __forceinline__ float bf2f(unsigned short h) {
    unsigned u = ((unsigned)h) << 16;
    return __builtin_bit_cast(float, u);
}

// ---------------- prep kernels ----------------

__global__ __launch_bounds__(256) void prep_q_kernel(const float* __restrict__ src,
                                                     const float* __restrict__ pos,
                                                     unsigned short* __restrict__ qb) {
    int t = blockIdx.x * 256 + threadIdx.x;
    int i4 = t * 4;
    float4 s = *reinterpret_cast<const float4*>(src + i4);
    float4 p = *reinterpret_cast<const float4*>(pos + i4);
    int n = i4 >> 11;
    int rem = i4 & 2047;
    int b = rem >> 8;
    int c = rem & 255;
    int out = (b * N_SEQ + n) * C_DIM + c;
    *reinterpret_cast<ushort4*>(qb + out) = make_ushort4(
        f2bf((s.x + p.x) * 0.0625f), f2bf((s.y + p.y) * 0.0625f),
        f2bf((s.z + p.z) * 0.0625f), f2bf((s.w + p.w) * 0.0625f));
}

// One block per (k,b,ntile of 64): writes kb row-major (+pos) and V in
// MFMA-fragment-tile layout: vfrag[pr][tile(32kv)][channel 256][kv-in-tile 32].
__global__ __launch_bounds__(256) void prep_kv_kernel(const float* __restrict__ matched,
                                                      const float* __restrict__ pos,
                                                      unsigned short* __restrict__ kb,
                                                      unsigned short* __restrict__ vfrag) {
    __shared__ unsigned short Vl[64][256];
    int blk = blockIdx.x;
    int nt = blk & 15, pr = blk >> 4;          // pr = k*8+b
    int k = pr >> 3, b = pr & 7;
    int n0 = nt * 64;
    int t = threadIdx.x;
    int c4 = (t & 63) * 4;
#pragma unroll
    for (int r = 0; r < 16; r++) {
        int nl = (t >> 6) * 16 + r;
        int n = n0 + nl;
        size_t mi = ((size_t)(k * N_SEQ + n) * B_SZ + b) * C_DIM + c4;
        float4 m = *reinterpret_cast<const float4*>(matched + mi);
        float4 p = *reinterpret_cast<const float4*>(pos + ((size_t)n * B_SZ + b) * C_DIM + c4);
        *reinterpret_cast<ushort4*>(kb + ((size_t)pr * N_SEQ + n) * C_DIM + c4) =
            make_ushort4(f2bf(m.x + p.x), f2bf(m.y + p.y), f2bf(m.z + p.z), f2bf(m.w + p.w));
        *reinterpret_cast<ushort4*>(&Vl[nl][c4]) =
            make_ushort4(f2bf(m.x), f2bf(m.y), f2bf(m.z), f2bf(m.w));
    }
    __syncthreads();
    // write two 32-kv fragment tiles (coalesced: thread t writes chunks t+256*kk)
    int j8 = t & 3, cbase = t >> 2;
#pragma unroll
    for (int h = 0; h < 2; h++) {
        unsigned short* tb = vfrag + ((size_t)(pr * 32 + nt * 2 + h)) * 8192;
#pragma unroll
        for (int kk = 0; kk < 4; kk++) {
            int c = cbase + 64 * kk;
            s16x8 v;
#pragma unroll
            for (int e = 0; e < 8; e++) v[e] = (short)Vl[h * 32 + j8 * 8 + e][c];
            *reinterpret_cast<s16x8*>(tb + (size_t)(t + 256 * kk) * 8) = v;
        }
    }
}

__global__ __launch_bounds__(256) void transpose_w_kernel(const float* __restrict__ W,
                                                          unsigned short* __restrict__ Wt,
                                                          int R, int Cn) {
    int idx = blockIdx.x * 256 + threadIdx.x;
    int c = idx / R;
    int r = idx - c * R;
    Wt[idx] = f2bf(W[(size_t)r * Cn + c]);
}

// ---------------- flash attention (KV-split x2, single barrier/iter) ----------------
// grid = 1024 blocks (XCD-aware, kidx minor), 256 threads (4 waves x 16 q-rows).
__global__ __launch_bounds__(256) void attn_kernel(const unsigned short* __restrict__ qb,
                                                   const unsigned short* __restrict__ kb,
                                                   const unsigned short* __restrict__ vfrag,
                                                   const float* __restrict__ mask,
                                                   unsigned short* __restrict__ op0,
                                                   unsigned short* __restrict__ op1,
                                                   float2* __restrict__ mlb) {
    __shared__ unsigned short Kl[2][8192];       // 32 KB: K tile, XOR-swizzled content
    __shared__ unsigned short VlF[2][8192];      // 32 KB: V fragment tile [ch 256][kv 32]
    __shared__ unsigned short Pl[4][16][36];     // 4.6 KB: wave-private P

    // XCD-aware decode: 4 kidx-sharers of one (b,qt,half) land on the same XCD
    int bx = blockIdx.x;
    int x = bx & 7;
    int j = bx >> 3;
    int kidx = j & 3;
    int g = (j >> 2) * 8 + x;        // 0..255
    int qt = g & 15;
    int b = (g >> 4) & 7;
    int half = g >> 7;
    int pr = kidx * 8 + b;

    int tid = threadIdx.x, wid = tid >> 6, lane = tid & 63;
    int l15 = lane & 15, lg = lane >> 4;
    int q0 = qt * 64 + wid * 16;
    int kvh = half * 512;

    // Q fragments
    s16x8 qf[8];
    const unsigned short* qrow = qb + ((size_t)(b * N_SEQ + q0 + l15)) * C_DIM + lg * 8;
#pragma unroll
    for (int cc = 0; cc < 8; cc++) qf[cc] = *reinterpret_cast<const s16x8*>(qrow + cc * 32);

    f32x4v oacc[16];
#pragma unroll
    for (int i = 0; i < 16; i++) oacc[i] = (f32x4v){0.f, 0.f, 0.f, 0.f};
    float mrun = -3e38f, lrun = 0.f;

    const unsigned short* kbp = kb + (size_t)pr * N_SEQ * C_DIM;
    const unsigned short* vfp = vfrag + ((size_t)(pr * 32 + half * 16)) * 8192;
    const float* mrow = mask + ((size_t)b * N_SEQ + q0 + l15) * N_SEQ + kvh;

    auto stage_k = [&](int kv0, unsigned short* buf) {
#pragma unroll
        for (int i = 0; i < 4; i++) {
            int ch = (wid * 4 + i) * 64 + lane;
            int r = ch >> 5;
            int ce = ((ch & 31) * 8) ^ ((r & 7) << 3);
            GLOAD_LDS16(kbp + (size_t)(kvh + kv0 + r) * C_DIM + ce, &buf[(wid * 4 + i) * 512]);
        }
    };
    auto stage_v = [&](int tile, unsigned short* buf) {
        const unsigned short* vsrc = vfp + (size_t)tile * 8192;
#pragma unroll
        for (int i = 0; i < 4; i++) {
            int cb = (wid * 4 + i) * 64;
            GLOAD_LDS16(vsrc + (size_t)(cb + lane) * 8, &buf[cb * 8]);
        }
    };

    // prologue: tile 0 K+V via gload_lds; mask tile 0 into regs
    stage_k(0, &Kl[0][0]);
    stage_v(0, &VlF[0][0]);
    f32x4v mc0 = *reinterpret_cast<const f32x4v*>(mrow + lg * 4);
    f32x4v mc1 = *reinterpret_cast<const f32x4v*>(mrow + 16 + lg * 4);

    int swz = (l15 & 7) << 3;
    for (int t = 0; t < 16; t++) {
        int cur = t & 1;
        int kv0 = t * 32;
        __syncthreads();                         // drains prefetch t; buffers [cur] ready
        // issue prefetch t+1 immediately (full-iter latency coverage)
        if (t + 1 < 16) {
            stage_k(kv0 + 32, &Kl[cur ^ 1][0]);
            stage_v(t + 1, &VlF[cur ^ 1][0]);
        }

        // S^T = K Q^T
        f32x4v s0 = {0.f, 0.f, 0.f, 0.f}, s1 = {0.f, 0.f, 0.f, 0.f};
        const unsigned short* KlB = &Kl[cur][0];
        __builtin_amdgcn_s_setprio(1);
#pragma unroll
        for (int cc = 0; cc < 8; cc++) {
            s16x8 k0 = *reinterpret_cast<const s16x8*>(KlB + l15 * 256 + ((cc * 32 + lg * 8) ^ swz));
            s16x8 k1 = *reinterpret_cast<const s16x8*>(KlB + (16 + l15) * 256 + ((cc * 32 + lg * 8) ^ swz));
            s0 = __builtin_amdgcn_mfma_f32_16x16x32_bf16(k0, qf[cc], s0, 0, 0, 0);
            s1 = __builtin_amdgcn_mfma_f32_16x16x32_bf16(k1, qf[cc], s1, 0, 0, 0);
        }
        __builtin_amdgcn_s_setprio(0);
#pragma unroll
        for (int jj = 0; jj < 4; jj++) { s0[jj] += mc0[jj]; s1[jj] += mc1[jj]; }
        // reload mask regs for t+1 (drained at next barrier)
        if (t + 1 < 16) {
            mc0 = *reinterpret_cast<const f32x4v*>(mrow + kv0 + 32 + lg * 4);
            mc1 = *reinterpret_cast<const f32x4v*>(mrow + kv0 + 48 + lg * 4);
        }

        // online softmax over kv (in-lane 8 + xor 16/32)
        float pm = fmaxf(fmaxf(fmaxf(s0[0], s0[1]), fmaxf(s0[2], s0[3])),
                         fmaxf(fmaxf(s1[0], s1[1]), fmaxf(s1[2], s1[3])));
        pm = fmaxf(pm, __shfl_xor(pm, 16));
        pm = fmaxf(pm, __shfl_xor(pm, 32));
        if (__any(pm > mrun + 8.f)) {            // defer-max
            float mn = fmaxf(mrun, pm);
            float sc = __expf(mrun - mn);
            mrun = mn;
            lrun *= sc;
#pragma unroll
            for (int ct = 0; ct < 16; ct++)
#pragma unroll
                for (int jj = 0; jj < 4; jj++) oacc[ct][jj] *= sc;
        }
        float p0[4], p1[4];
#pragma unroll
        for (int jj = 0; jj < 4; jj++) {
            p0[jj] = __expf(s0[jj] - mrun);
            p1[jj] = __expf(s1[jj] - mrun);
        }
        float ps = (p0[0] + p0[1]) + (p0[2] + p0[3]) + (p1[0] + p1[1]) + (p1[2] + p1[3]);
        ps += __shfl_xor(ps, 16);
        ps += __shfl_xor(ps, 32);
        lrun += ps;

        // P^T -> Pl (wave-private; compiler inserts lgkmcnt) -> A-fragment
        *reinterpret_cast<ushort4*>(&Pl[wid][l15][lg * 4]) =
            make_ushort4(f2bf(p0[0]), f2bf(p0[1]), f2bf(p0[2]), f2bf(p0[3]));
        *reinterpret_cast<ushort4*>(&Pl[wid][l15][16 + lg * 4]) =
            make_ushort4(f2bf(p1[0]), f2bf(p1[1]), f2bf(p1[2]), f2bf(p1[3]));
        s16x8 pf = *reinterpret_cast<const s16x8*>(&Pl[wid][l15][lg * 8]);

        // O^T += V^T P^T; A-fragment = VlF[ch = ct*16+l15][kv = lg*8..]
        const unsigned short* VlB = &VlF[cur][0];
        __builtin_amdgcn_s_setprio(1);
#pragma unroll
        for (int ct = 0; ct < 16; ct++) {
            s16x8 af = *reinterpret_cast<const s16x8*>(VlB + (ct * 16 + l15) * 32 + lg * 8);
            oacc[ct] = __builtin_amdgcn_mfma_f32_16x16x32_bf16(af, pf, oacc[ct], 0, 0, 0);
        }
        __builtin_amdgcn_s_setprio(0);
    }

    float inv = 1.0f / lrun;
    unsigned short* Op = half ? op1 : op0;
    size_t orow = ((size_t)(b * N_SEQ + q0 + l15)) * (K_HEADS * C_DIM) + kidx * C_DIM + lg * 4;
#pragma unroll
    for (int ct = 0; ct < 16; ct++) {
        *reinterpret_cast<ushort4*>(Op + orow + ct * 16) =
            make_ushort4(f2bf(oacc[ct][0] * inv), f2bf(oacc[ct][1] * inv),
                         f2bf(oacc[ct][2] * inv), f2bf(oacc[ct][3] * inv));
    }
    if (lg == 0)
        mlb[((size_t)(half * 4 + kidx) * 8 + b) * N_SEQ + q0 + l15] = make_float2(mrun, lrun);
}

// ---------------- combine two KV-half partials ----------------
__global__ __launch_bounds__(256) void combine_kernel(const unsigned short* __restrict__ op0,
                                                      const unsigned short* __restrict__ op1,
                                                      const float2* __restrict__ mlb,
                                                      unsigned short* __restrict__ att) {
    int t = blockIdx.x * 256 + threadIdx.x;
    int kidx = (t >> 5) & 3;
    int bn = t >> 7;
    int n = bn & 1023, b = bn >> 10;
    float2 e0 = mlb[((size_t)kidx * 8 + b) * N_SEQ + n];
    float2 e1 = mlb[((size_t)(4 + kidx) * 8 + b) * N_SEQ + n];
    float M = fmaxf(e0.x, e1.x);
    float w0 = e0.y * __expf(e0.x - M);
    float w1 = e1.y * __expf(e1.x - M);
    float r = 1.0f / (w0 + w1);
    w0 *= r;
    w1 *= r;
    s16x8 a = *reinterpret_cast<const s16x8*>(op0 + (size_t)t * 8);
    s16x8 c = *reinterpret_cast<const s16x8*>(op1 + (size_t)t * 8);
    s16x8 o;
#pragma unroll
    for (int i = 0; i < 8; i++)
        o[i] = (short)f2bf(w0 * bf2f((unsigned short)a[i]) + w1 * bf2f((unsigned short)c[i]));
    *reinterpret_cast<s16x8*>(att + (size_t)t * 8) = o;
}

// ---------------- GEMM: C = A(MxK) * Bt(NxK)^T + bias ----------------
template <int BM, int BN, int RELU, int OUTBF>
__global__ __launch_bounds__(256) void gemm_bt_kernel(const unsigned short* __restrict__ A,
                                                      const unsigned short* __restrict__ Bt,
                                                      const float* __restrict__ bias,
                                                      float* __restrict__ Cf,
                                                      unsigned short* __restrict__ Cb,
                                                      int M, int Nn, int Kd) {
    constexpr int WAVES_N = (BM == 128) ? 2 : 4;
    constexpr int WN = BN / WAVES_N;
    constexpr int NT = WN / 16;
    constexpr int TILE = (BM + BN) * 64;
    constexpr int CALLS = (BM + BN) / 32;
    __shared__ unsigned short Sl[2][TILE];
    int tm0 = blockIdx.y * BM, tn0 = blockIdx.x * BN;
    int tid = threadIdx.x, wid = tid >> 6, lane = tid & 63;
    int l15 = lane & 15, lg = lane >> 4;
    int wm = (wid / WAVES_N) * 64, wn = (wid % WAVES_N) * WN;

    f32x4v acc[4][NT];
#pragma unroll
    for (int i = 0; i < 4; i++)
#pragma unroll
        for (int j = 0; j < NT; j++) acc[i][j] = (f32x4v){0.f, 0.f, 0.f, 0.f};

    auto stage = [&](int k0, unsigned short* buf) {
#pragma unroll
        for (int i = 0; i < CALLS; i++) {
            int chb = (i * 4 + wid) * 64;
            int ch = chb + lane;
            const unsigned short* src;
            if (chb < BM * 8) {
                int r = ch >> 3;
                int c8 = ((ch & 7) * 8) ^ ((r & 7) << 3);
                src = A + (size_t)(tm0 + r) * Kd + k0 + c8;
            } else {
                int ch2 = ch - BM * 8;
                int r = ch2 >> 3;
                int c8 = ((ch2 & 7) * 8) ^ ((r & 7) << 3);
                src = Bt + (size_t)(tn0 + r) * Kd + k0 + c8;
            }
            GLOAD_LDS16(src, buf + chb * 8);
        }
    };

    stage(0, &Sl[0][0]);
    int nk = Kd >> 6;
    int swz = (l15 & 7) << 3;
    for (int kt = 0; kt < nk; kt++) {
        int cur = kt & 1;
        __syncthreads();
        if (kt + 1 < nk) stage((kt + 1) * 64, &Sl[cur ^ 1][0]);
        const unsigned short* SA = &Sl[cur][0];
        const unsigned short* SB = SA + BM * 64;
        s16x8 af[4][2], bf[NT][2];
#pragma unroll
        for (int mt = 0; mt < 4; mt++)
#pragma unroll
            for (int h = 0; h < 2; h++)
                af[mt][h] = *reinterpret_cast<const s16x8*>(
                    SA + (wm + mt * 16 + l15) * 64 + ((h * 32 + lg * 8) ^ swz));
#pragma unroll
        for (int nt = 0; nt < NT; nt++)
#pragma unroll
            for (int h = 0; h < 2; h++)
                bf[nt][h] = *reinterpret_cast<const s16x8*>(
                    SB + (wn + nt * 16 + l15) * 64 + ((h * 32 + lg * 8) ^ swz));
        __builtin_amdgcn_s_setprio(1);
#pragma unroll
        for (int mt = 0; mt < 4; mt++)
#pragma unroll
            for (int nt = 0; nt < NT; nt++) {
                acc[mt][nt] = __builtin_amdgcn_mfma_f32_16x16x32_bf16(af[mt][0], bf[nt][0], acc[mt][nt], 0, 0, 0);
                acc[mt][nt] = __builtin_amdgcn_mfma_f32_16x16x32_bf16(af[mt][1], bf[nt][1], acc[mt][nt], 0, 0, 0);
            }
        __builtin_amdgcn_s_setprio(0);
    }

#pragma unroll
    for (int mt = 0; mt < 4; mt++) {
#pragma unroll
        for (int nt = 0; nt < NT; nt++) {
#pragma unroll
            for (int j = 0; j < 4; j++) {
                int row = tm0 + wm + mt * 16 + lg * 4 + j;
                int col = tn0 + wn + nt * 16 + l15;
                float v = acc[mt][nt][j] + bias[col];
                if (RELU) v = fmaxf(v, 0.f);
                if (OUTBF) Cb[(size_t)row * Nn + col] = f2bf(v);
                else       Cf[(size_t)row * Nn + col] = v;
            }
        }
    }
}

// ---------------- fused residual + LayerNorm ----------------
__global__ __launch_bounds__(256) void ln1_kernel(const float* __restrict__ src,
                                                  const float* __restrict__ recT,
                                                  const float* __restrict__ g,
                                                  const float* __restrict__ be,
                                                  float* __restrict__ outf,
                                                  unsigned short* __restrict__ outb) {
    int r = blockIdx.x * 4 + (threadIdx.x >> 6);
    int lane = threadIdx.x & 63;
    int n = r >> 3, b = r & 7;
    int c = lane * 4;
    float4 xs = *reinterpret_cast<const float4*>(src + (size_t)r * C_DIM + c);
    float4 xr = *reinterpret_cast<const float4*>(recT + ((size_t)(b * N_SEQ + n)) * C_DIM + c);
    float x[4] = {xs.x + xr.x, xs.y + xr.y, xs.z + xr.z, xs.w + xr.w};
    float s = x[0] + x[1] + x[2] + x[3];
    float q = x[0] * x[0] + x[1] * x[1] + x[2] * x[2] + x[3] * x[3];
#pragma unroll
    for (int d = 1; d < 64; d <<= 1) {
        s += __shfl_xor(s, d);
        q += __shfl_xor(q, d);
    }
    float mean = s * (1.f / 256.f);
    float var = q * (1.f / 256.f) - mean * mean;
    float rstd = rsqrtf(var + 1e-5f);
    float4 gv = *reinterpret_cast<const float4*>(g + c);
    float4 bv = *reinterpret_cast<const float4*>(be + c);
    float y0 = (x[0] - mean) * rstd * gv.x + bv.x;
    float y1 = (x[1] - mean) * rstd * gv.y + bv.y;
    float y2 = (x[2] - mean) * rstd * gv.z + bv.z;
    float y3 = (x[3] - mean) * rstd * gv.w + bv.w;
    *reinterpret_cast<float4*>(outf + (size_t)r * C_DIM + c) = make_float4(y0, y1, y2, y3);
    *reinterpret_cast<ushort4*>(outb + (size_t)r * C_DIM + c) =
        make_ushort4(f2bf(y0), f2bf(y1), f2bf(y2), f2bf(y3));
}

__global__ __launch_bounds__(256) void ln2_kernel(const float* __restrict__ rec1f,
                                                  const float* __restrict__ ffn,
                                                  const float* __restrict__ g,
                                                  const float* __restrict__ be,
                                                  float* __restrict__ out) {
    int r = blockIdx.x * 4 + (threadIdx.x >> 6);
    int lane = threadIdx.x & 63;
    int c = lane * 4;
    size_t base = (size_t)r * C_DIM + c;
    float4 xa = *reinterpret_cast<const float4*>(rec1f + base);
    float4 xb = *reinterpret_cast<const float4*>(ffn + base);
    float x[4] = {xa.x + xb.x, xa.y + xb.y, xa.z + xb.z, xa.w + xb.w};
    float s = x[0] + x[1] + x[2] + x[3];
    float q = x[0] * x[0] + x[1] * x[1] + x[2] * x[2] + x[3] * x[3];
#pragma unroll
    for (int d = 1; d < 64; d <<= 1) {
        s += __shfl_xor(s, d);
        q += __shfl_xor(q, d);
    }
    float mean = s * (1.f / 256.f);
    float var = q * (1.f / 256.f) - mean * mean;
    float rstd = rsqrtf(var + 1e-5f);
    float4 gv = *reinterpret_cast<const float4*>(g + c);
    float4 bv = *reinterpret_cast<const float4*>(be + c);
    *reinterpret_cast<float4*>(out + base) = make_float4(
        (x[0] - mean) * rstd * gv.x + bv.x,
        (x[1] - mean) * rstd * gv.y + bv.y,
        (x[2] - mean) * rstd * gv.z + bv.z,
        (x[3] - mean) * rstd * gv.w + bv.w);
}

// ---------------- launch ----------------

extern "C" void kernel_launch(void* const* d_in, const int* in_sizes, int n_in,
                              void* d_out, int out_size, void* d_ws, size_t ws_size,
                              hipStream_t stream) {
    const float* src   = (const float*)d_in[0];
    const float* match = (const float*)d_in[1];
    const float* pos   = (const float*)d_in[2];
    const float* mask  = (const float*)d_in[3];
    const float* Wagg  = (const float*)d_in[4];
    const float* bagg  = (const float*)d_in[5];
    const float* W1    = (const float*)d_in[6];
    const float* b1    = (const float*)d_in[7];
    const float* W2    = (const float*)d_in[8];
    const float* b2    = (const float*)d_in[9];
    const float* g1    = (const float*)d_in[10];
    const float* be1   = (const float*)d_in[11];
    const float* g2    = (const float*)d_in[12];
    const float* be2   = (const float*)d_in[13];

    char* ws = (char*)d_ws;
    unsigned short* qb    = (unsigned short*)(ws + 0);          //  4 MB (B,N,C) bf16 pre-scaled
    unsigned short* kb    = (unsigned short*)(ws + 4194304);    // 16 MB (K*B,N,C) bf16
    unsigned short* vfrag = (unsigned short*)(ws + 20971520);   // 16 MB V fragment tiles
    unsigned short* att   = (unsigned short*)(ws + 37748736);   // 16 MB (B,N,K*C) bf16; = op0
    float*          rec_t = (float*)(ws + 57147392);            // 8 MB (B*N,C) f32
    float*          rec1f = (float*)(ws + 65536000);            // 8 MB (N*B,C) f32
    unsigned short* rec1b = (unsigned short*)(ws + 73924608);   // 4 MB bf16
    unsigned short* WaggT = (unsigned short*)(ws + 54525952);   // 0.5 MB
    unsigned short* W1T   = (unsigned short*)(ws + 55050240);   // 1 MB
    unsigned short* W2T   = (unsigned short*)(ws + 56098816);   // 1 MB
    // attention-phase aliases (dead regions during attn):
    unsigned short* op0   = att;                                // 16 MB partial half0 (combined in-place)
    unsigned short* op1   = (unsigned short*)(ws + 57147392);   // 16 MB partial half1 (over rec_t+rec1f)
    float2*         mlb   = (float2*)(ws + 73924608);           // 512 KB (over rec1b)
    unsigned short* hid   = (unsigned short*)(ws + 4194304);    // 32 MB, aliases kb+vfrag (dead post-attn)
    float*          ffn   = (float*)(ws + 57147392);            // 8 MB, aliases rec_t (dead)
    float* outp = (float*)d_out;

    prep_q_kernel<<<2048, 256, 0, stream>>>(src, pos, qb);
    prep_kv_kernel<<<512, 256, 0, stream>>>(match, pos, kb, vfrag);
    transpose_w_kernel<<<1024, 256, 0, stream>>>(Wagg, WaggT, K_HEADS * C_DIM, C_DIM);
    transpose_w_kernel<<<2048, 256, 0, stream>>>(W1, W1T, C_DIM, FF_DIM);
    transpose_w_kernel<<<2048, 256, 0, stream>>>(W2, W2T, FF_DIM, C_DIM);

    attn_kernel<<<1024, 256, 0, stream>>>(qb, kb, vfrag, mask, op0, op1, mlb);
    combine_kernel<<<4096, 256, 0, stream>>>(op0, op1, mlb, att);

    gemm_bt_kernel<64, 128, 0, 0><<<dim3(2, 128), 256, 0, stream>>>(
        att, WaggT, bagg, rec_t, nullptr, B_SZ * N_SEQ, C_DIM, K_HEADS * C_DIM);
    ln1_kernel<<<2048, 256, 0, stream>>>(src, rec_t, g1, be1, rec1f, rec1b);
    gemm_bt_kernel<128, 128, 1, 1><<<dim3(16, 64), 256, 0, stream>>>(
        rec1b, W1T, b1, nullptr, hid, N_SEQ * B_SZ, FF_DIM, C_DIM);
    gemm_bt_kernel<64, 128, 0, 0><<<dim3(2, 128), 256, 0, stream>>>(
        hid, W2T, b2, ffn, nullptr, N_SEQ * B_SZ, C_DIM, FF_DIM);
    ln2_kernel<<<2048, 256, 0, stream>>>(rec1f, ffn, g2, be2, outp);
}